// Round 12
// baseline (2646.050 us; speedup 1.0000x reference)
//
#include <hip/hip_runtime.h>
#include <hip/hip_bf16.h>
#include <cstdint>
#include <cstddef>

#define B_   8192
#define D_   2048
#define H1_  1024
#define H2_  512
#define G_   512
#define T_   2
#define E_   6
#define EC_  4

typedef __bf16 bf16_t;
typedef __attribute__((ext_vector_type(8))) __bf16 bf16x8;
typedef __attribute__((ext_vector_type(4))) float f32x4;

// ---------------------------------------------------------------------------
// async global->LDS, 16B per lane. LDS dest is wave-uniform base + lane*16.
// ---------------------------------------------------------------------------
__device__ __forceinline__ void gload_lds16(const bf16_t* g, bf16_t* l) {
    __builtin_amdgcn_global_load_lds(
        (const __attribute__((address_space(1))) bf16_t*)g,
        (__attribute__((address_space(3))) bf16_t*)l,
        16, 0, 0);
}

// ---------------------------------------------------------------------------
// unified prep: z 0..5 transpose We1 slices, 6..11 We2, 12..13 Wg1,
// 14..17 cast x -> bf16. Guards are block-uniform. grid (32,64,18), blk (32,8).
// ---------------------------------------------------------------------------
__global__ __launch_bounds__(256) void prep_kernel(
    const float* __restrict__ x,   const float* __restrict__ We1,
    const float* __restrict__ We2, const float* __restrict__ Wg1,
    bf16_t* __restrict__ x_bf, bf16_t* __restrict__ w1t,
    bf16_t* __restrict__ w2t,  bf16_t* __restrict__ wgt)
{
    __shared__ float tile[32][33];
    const int z  = blockIdx.z;
    const int bx = blockIdx.x, by = blockIdx.y;
    const int tx = threadIdx.x, ty = threadIdx.y;

    const float* src; bf16_t* dst; int R, C;
    if (z < 6) {
        src = We1 + (size_t)z * D_ * H1_;  dst = w1t + (size_t)z * H1_ * D_;
        R = D_;  C = H1_;
    } else if (z < 12) {
        if (bx >= 16 || by >= 32) return;
        src = We2 + (size_t)(z - 6) * H1_ * H2_;
        dst = w2t + (size_t)(z - 6) * H2_ * H1_;
        R = H1_; C = H2_;
    } else if (z < 14) {
        if (bx >= 16) return;
        src = Wg1 + (size_t)(z - 12) * D_ * G_;
        dst = wgt + (size_t)(z - 12) * G_ * D_;
        R = D_;  C = G_;
    } else {
        int i = ((z - 14) * 2048 + by * 32 + bx) * 256 + ty * 32 + tx;
        const float4* s = (const float4*)x + (size_t)i * 2;
        float4 a = s[0], b = s[1];
        bf16x8 o;
        o[0] = (bf16_t)a.x; o[1] = (bf16_t)a.y; o[2] = (bf16_t)a.z; o[3] = (bf16_t)a.w;
        o[4] = (bf16_t)b.x; o[5] = (bf16_t)b.y; o[6] = (bf16_t)b.z; o[7] = (bf16_t)b.w;
        *(bf16x8*)(x_bf + (size_t)i * 8) = o;
        return;
    }
    const int c0 = bx * 32, r0 = by * 32;
#pragma unroll
    for (int i = 0; i < 32; i += 8)
        tile[ty + i][tx] = src[(size_t)(r0 + ty + i) * C + (c0 + tx)];
    __syncthreads();
#pragma unroll
    for (int i = 0; i < 32; i += 8)
        dst[(size_t)(c0 + ty + i) * R + (r0 + tx)] = (bf16_t)tile[tx][ty + i];
}

// ---------------------------------------------------------------------------
// 256x256-tile, BK=32, 4-phase single-barrier GEMM, 2 blocks/CU (round 12):
//   C = relu(A(M,K) * Bt(N,K)^T + bias), bf16 in/out, fp32 MFMA accumulate.
// r11's 4-phase structure with BK halved 64->32: dbuf LDS = 64 KB ->
// 2 blocks/CU -> 4 waves/SIMD from TWO INDEPENDENT blocks, so one block's
// barrier waits are filled by the other block's MFMA (r4-proven mechanism).
// 8 waves (2Mx4N), per-wave 128x64, acc = 128 AGPR; phase = m-half of one
// K-tile: {4 A-reads [+4 B-reads at mh==0] || 1 tile stage -> barrier ->
// lgkm(0) -> 16 MFMA}.
// Wait ledger (2 loads per stage slot): prologue {A0,B0,B1}=6 -> vmcnt(2);
// end-p1 vmcnt(2) completes B(kt1),A(kt1) (needed p2), leaves B(kt0+2);
// end-p3 vmcnt(2) completes tile kt0+2 (needed next p0), leaves B(kt0+3);
// tail iter end-p1 vmcnt(0). Buffer overwrites keep the >=1-barrier margin
// validated in r8/r11. Swizzle: chunk ^= (row>>1)&3 (r4-verified BK32
// family, conflict-free) on BOTH stage-source and ds_read.
// bias: e<6 -> be1+e*H1, e==6 -> bg1.
// Requires: M%256==0, N%256==0, K%64==0, K/32>=4, gridX*gridY%8==0.
// ---------------------------------------------------------------------------
__global__ __launch_bounds__(512, 4) void gemm256_4p32(
    const bf16_t* __restrict__ A, const bf16_t* __restrict__ Bt,
    const float* __restrict__ be1, const float* __restrict__ bg1,
    bf16_t* __restrict__ C, int M, int N, int K, long long strideA)
{
    const int e = blockIdx.z;
    A  += (size_t)e * (size_t)strideA;
    Bt += (size_t)e * (size_t)N * (size_t)K;
    C  += (size_t)e * (size_t)M * (size_t)N;
    const float* bias = (e < 6) ? (be1 + (size_t)e * H1_) : bg1;

    // T1: XCD swizzle within this z-slice (nwg % 8 == 0 by launch contract)
    const int gx  = gridDim.x;
    const int nwg = gx * gridDim.y;
    const int lin = blockIdx.y * gx + blockIdx.x;
    const int swz = (lin & 7) * (nwg >> 3) + (lin >> 3);
    const int row0 = (swz / gx) * 256;
    const int col0 = (swz % gx) * 256;

    __shared__ bf16_t lsA[2][8192];   // [dbuf][256 rows x 32], 16 KB each
    __shared__ bf16_t lsB[2][8192];   // total 64 KB -> 2 blocks/CU

    const int tid  = threadIdx.x;
    const int lane = tid & 63;
    const int wave = tid >> 6;        // 0..7
    const int wr   = wave >> 2;       // 0..1 : M-half (128 rows)
    const int wc   = wave & 3;        // 0..3 : N-quarter (64 cols)

    // ---- staging: tile 256x32 = 1024 chunks(16B), slots l*512+tid ----------
    // slot -> row = slot>>2, phys chunk = slot&3, logical c = pc ^ ((row>>1)&3)
    size_t offG[2];
    int    ldsOff[2];
#pragma unroll
    for (int l = 0; l < 2; ++l) {
        int idx = l * 512 + tid;
        int r   = idx >> 2;
        int c   = (idx & 3) ^ ((r >> 1) & 3);
        offG[l]   = (size_t)r * (size_t)K + (size_t)(c * 8);
        ldsOff[l] = l * 4096 + wave * 512;        // elements, wave-uniform
    }
    const bf16_t* gA = A  + (size_t)row0 * (size_t)K;
    const bf16_t* gB = Bt + (size_t)col0 * (size_t)K;

    // ---- fragment read addressing (elements), same XOR involution ----------
    const int xch  = ((lane >> 4) ^ ((lane >> 1) & 3)) << 3;
    const int aoff = (wr * 128 + (lane & 15)) * 32 + xch;
    const int boff = (wc * 64  + (lane & 15)) * 32 + xch;

    f32x4 acc[8][4];
#pragma unroll
    for (int m = 0; m < 8; ++m)
#pragma unroll
        for (int n = 0; n < 4; ++n)
            acc[m][n] = (f32x4){0.f, 0.f, 0.f, 0.f};

    const int nt    = K >> 5;         // K-tiles of 32
    const int niter = nt >> 1;        // 2 K-tiles per iteration

#define STAGE_A(dst, kt) do {                                                 \
    _Pragma("unroll")                                                         \
    for (int l_ = 0; l_ < 2; ++l_)                                            \
        gload_lds16(gA + (size_t)((kt) * 32) + offG[l_],                      \
                    &lsA[dst][ldsOff[l_]]);                                   \
} while (0)

#define STAGE_B(dst, kt) do {                                                 \
    _Pragma("unroll")                                                         \
    for (int l_ = 0; l_ < 2; ++l_)                                            \
        gload_lds16(gB + (size_t)((kt) * 32) + offG[l_],                      \
                    &lsB[dst][ldsOff[l_]]);                                   \
} while (0)

// phase mh (m-half) of dbuf d: {4 A-reads [+4 B-reads if mh==0]; stage;
// optional vmcnt; barrier; lgkm(0); 16 MFMA}. WAITV precedes the barrier.
#define PHASE(d, mh, STMT, WAITV) do {                                        \
    bf16x8 af[4];                                                             \
    _Pragma("unroll")                                                         \
    for (int q_ = 0; q_ < 4; ++q_)                                            \
        af[q_] = *(const bf16x8*)&lsA[d][aoff + ((mh)*4+q_) * 512];           \
    if ((mh) == 0) {                                                          \
        _Pragma("unroll")                                                     \
        for (int n_ = 0; n_ < 4; ++n_)                                        \
            bfr[n_] = *(const bf16x8*)&lsB[d][boff + n_ * 512];               \
    }                                                                         \
    STMT;                                                                     \
    WAITV;                                                                    \
    __builtin_amdgcn_sched_barrier(0);                                        \
    __builtin_amdgcn_s_barrier();                                             \
    asm volatile("s_waitcnt lgkmcnt(0)" ::: "memory");                        \
    __builtin_amdgcn_sched_barrier(0);                                        \
    __builtin_amdgcn_s_setprio(1);                                            \
    _Pragma("unroll")                                                         \
    for (int q_ = 0; q_ < 4; ++q_)                                            \
        _Pragma("unroll")                                                     \
        for (int n_ = 0; n_ < 4; ++n_)                                        \
            acc[(mh)*4+q_][n_] = __builtin_amdgcn_mfma_f32_16x16x32_bf16(     \
                     af[q_], bfr[n_], acc[(mh)*4+q_][n_], 0, 0, 0);           \
    __builtin_amdgcn_s_setprio(0);                                            \
    __builtin_amdgcn_sched_barrier(0);                                        \
} while (0)

    // ---- prologue: A(0),B(0) -> buf0; B(1) -> buf1; drain to 2 -------------
    STAGE_A(0, 0); STAGE_B(0, 0); STAGE_B(1, 1);
    asm volatile("s_waitcnt vmcnt(2)" ::: "memory");   // A(0),B(0) complete
    __builtin_amdgcn_sched_barrier(0);
    __builtin_amdgcn_s_barrier();
    __builtin_amdgcn_sched_barrier(0);

    // ---- main loop: iter i computes kt0=2i (buf0, p0-p1), kt1=2i+1 (buf1) --
    for (int i = 0; i < niter; ++i) {
        const int kt0 = 2 * i, kt1 = 2 * i + 1;
        const bool stg = (i + 1 < niter);
        bf16x8 bfr[4];

        PHASE(0, 0, { STAGE_A(1, kt1); }, {});
        PHASE(0, 1, { if (stg) STAGE_B(0, kt0 + 2); },
              { if (stg) { asm volatile("s_waitcnt vmcnt(2)" ::: "memory"); }
                else     { asm volatile("s_waitcnt vmcnt(0)" ::: "memory"); } });
        PHASE(1, 0, { if (stg) STAGE_A(0, kt0 + 2); }, {});
        PHASE(1, 1, { if (stg) STAGE_B(1, kt0 + 3); },
              { if (stg) { asm volatile("s_waitcnt vmcnt(2)" ::: "memory"); } });
    }
#undef PHASE
#undef STAGE_A
#undef STAGE_B

    // ---- epilogue: C/D layout col = lane&15, row = (lane>>4)*4 + j ----------
    const int crb = row0 + wr * 128 + ((lane >> 4) << 2);
    const int ccb = col0 + wc * 64  + (lane & 15);
#pragma unroll
    for (int n = 0; n < 4; ++n) {
        const int cc = ccb + n * 16;
        const float bv = bias[cc];
#pragma unroll
        for (int m = 0; m < 8; ++m) {
            const int rb = crb + m * 16;
#pragma unroll
            for (int j = 0; j < 4; ++j) {
                float v = acc[m][n][j] + bv;
                v = v > 0.f ? v : 0.f;
                C[(size_t)(rb + j) * N + cc] = (bf16_t)v;
            }
        }
    }
}

// ---------------------------------------------------------------------------
// r4-proven 128x256 GEMM, 2 blocks/CU — GEMM2 (writes h2 bf16).
// ---------------------------------------------------------------------------
__global__ __launch_bounds__(512, 4) void gemm_bn256_bias_relu(
    const bf16_t* __restrict__ A, const bf16_t* __restrict__ Bt,
    const float* __restrict__ bias, bf16_t* __restrict__ C,
    int M, int N, int K, long long strideA)
{
    const int e = blockIdx.z;
    A    += (size_t)e * (size_t)strideA;
    Bt   += (size_t)e * (size_t)N * (size_t)K;
    bias += (size_t)e * (size_t)N;
    C    += (size_t)e * (size_t)M * (size_t)N;

    const int gx  = gridDim.x;
    const int nwg = gx * gridDim.y;
    const int lin = blockIdx.y * gx + blockIdx.x;
    const int swz = (lin & 7) * (nwg >> 3) + (lin >> 3);
    const int row0 = (swz / gx) * 128;
    const int col0 = (swz % gx) * 256;

    __shared__ bf16_t lsA[3][128 * 32];   // 3 x 8 KB
    __shared__ bf16_t lsB[3][256 * 32];   // 3 x 16 KB   -> 72 KB total

    const int tid  = threadIdx.x;
    const int lane = tid & 63;
    const int wave = tid >> 6;        // 0..7
    const int wr   = wave >> 2;       // 0..1 : 64-row half
    const int wc   = wave & 3;        // 0..3 : 64-col quarter

    size_t offA, offB0, offB1;
    {
        int rA = tid >> 2, pA = tid & 3;
        offA = (size_t)rA * (size_t)K + (size_t)(((pA ^ (rA >> 1)) & 3) * 8);
        int r0_ = tid >> 2, p0_ = tid & 3;
        offB0 = (size_t)r0_ * (size_t)K + (size_t)(((p0_ ^ (r0_ >> 1)) & 3) * 8);
        int r1_ = (512 + tid) >> 2, p1_ = tid & 3;
        offB1 = (size_t)r1_ * (size_t)K + (size_t)(((p1_ ^ (r1_ >> 1)) & 3) * 8);
    }
    const int ldsA_off = wave * 512;
    const int ldsB0off = wave * 512;
    const int ldsB1off = 4096 + wave * 512;

    const bf16_t* gA = A  + (size_t)row0 * (size_t)K;
    const bf16_t* gB = Bt + (size_t)col0 * (size_t)K;

    const int xch  = ((lane >> 4) ^ ((lane >> 1) & 3)) << 3;
    const int aoff = (wr * 64 + (lane & 15)) * 32 + xch;
    const int boff = (wc * 64 + (lane & 15)) * 32 + xch;

    f32x4 acc[4][4];
#pragma unroll
    for (int m = 0; m < 4; ++m)
#pragma unroll
        for (int n = 0; n < 4; ++n)
            acc[m][n] = (f32x4){0.f, 0.f, 0.f, 0.f};

    const int nt = K >> 5;

#define STAGE(t_, c_) do {                                                    \
    const size_t kk_ = (size_t)(t_) * 32;                                     \
    gload_lds16(gA + kk_ + offA,  &lsA[c_][ldsA_off]);                        \
    gload_lds16(gB + kk_ + offB0, &lsB[c_][ldsB0off]);                        \
    gload_lds16(gB + kk_ + offB1, &lsB[c_][ldsB1off]);                        \
} while (0)

    STAGE(0, 0); STAGE(1, 1); STAGE(2, 2);
    asm volatile("s_waitcnt vmcnt(6)" ::: "memory");
    __builtin_amdgcn_s_barrier();
    __builtin_amdgcn_sched_barrier(0);

    int c = 0;
    for (int t = 0; t < nt; ++t) {
        bf16x8 a[4], b[4];
#pragma unroll
        for (int m = 0; m < 4; ++m)
            a[m] = *(const bf16x8*)&lsA[c][aoff + m * 512];
#pragma unroll
        for (int n = 0; n < 4; ++n)
            b[n] = *(const bf16x8*)&lsB[c][boff + n * 512];
        asm volatile("s_waitcnt lgkmcnt(0)" ::: "memory");
        __builtin_amdgcn_sched_barrier(0);
        __builtin_amdgcn_s_barrier();
        __builtin_amdgcn_sched_barrier(0);
        if (t + 3 < nt) STAGE(t + 3, c);
        __builtin_amdgcn_sched_barrier(0);
        __builtin_amdgcn_s_setprio(1);
#pragma unroll
        for (int m = 0; m < 4; ++m)
#pragma unroll
            for (int n = 0; n < 4; ++n)
                acc[m][n] = __builtin_amdgcn_mfma_f32_16x16x32_bf16(
                                a[m], b[n], acc[m][n], 0, 0, 0);
        __builtin_amdgcn_s_setprio(0);
        __builtin_amdgcn_sched_barrier(0);
        if (t + 3 < nt) { asm volatile("s_waitcnt vmcnt(6)" ::: "memory"); }
        else            { asm volatile("s_waitcnt vmcnt(0)" ::: "memory"); }
        __builtin_amdgcn_sched_barrier(0);
        __builtin_amdgcn_s_barrier();
        __builtin_amdgcn_sched_barrier(0);
        c = (c == 2) ? 0 : c + 1;
    }
#undef STAGE

    const int crb = row0 + wr * 64 + ((lane >> 4) << 2);
    const int ccb = col0 + wc * 64 + (lane & 15);
#pragma unroll
    for (int n = 0; n < 4; ++n) {
        const int cc = ccb + n * 16;
        const float bv = bias[cc];
#pragma unroll
        for (int m = 0; m < 4; ++m) {
            const int rb = crb + m * 16;
#pragma unroll
            for (int j = 0; j < 4; ++j) {
                float v = acc[m][n][j] + bv;
                v = v > 0.f ? v : 0.f;
                C[(size_t)(rb + j) * N + cc] = (bf16_t)v;
            }
        }
    }
}

// ---------------------------------------------------------------------------
// fused gate + combine (r9-proven): per wave, one (t,b) row.
// ---------------------------------------------------------------------------
__global__ __launch_bounds__(256) void gate_combine_kernel(
    const bf16_t* __restrict__ h1, const bf16_t* __restrict__ h2,
    const float* __restrict__ Wgs, float* __restrict__ out)
{
    int wid  = blockIdx.x * 4 + (threadIdx.x >> 6);   // t*B + b
    int lane = threadIdx.x & 63;
    int t = wid >> 13;                                // B_ = 8192
    int b = wid & (B_ - 1);

    const bf16_t* grow = h1 + ((size_t)(6 * B_) + b) * 1024 + t * G_;
    bf16x8 gv = *(const bf16x8*)&grow[lane * 8];
    const float* W = Wgs + (size_t)t * G_ * EC_;
    float a0 = 0.f, a1 = 0.f, a2 = 0.f, a3 = 0.f;
#pragma unroll
    for (int i = 0; i < 8; ++i) {
        float gvf = (float)gv[i];
        const float4 w = *(const float4*)&W[(size_t)(lane * 8 + i) * 4];
        a0 += gvf * w.x; a1 += gvf * w.y; a2 += gvf * w.z; a3 += gvf * w.w;
    }
#pragma unroll
    for (int off = 32; off; off >>= 1) {
        a0 += __shfl_xor(a0, off);
        a1 += __shfl_xor(a1, off);
        a2 += __shfl_xor(a2, off);
        a3 += __shfl_xor(a3, off);
    }
    float m  = fmaxf(fmaxf(a0, a1), fmaxf(a2, a3));
    float e0 = expf(a0 - m), e1 = expf(a1 - m), e2 = expf(a2 - m), e3 = expf(a3 - m);
    float inv = 1.f / (e0 + e1 + e2 + e3);
    float g0 = e0 * inv, g1 = e1 * inv, g2 = e2 * inv, g3 = e3 * inv;

    int o0 = lane * 8;                                // H2 = 512 = 64*8
    const bf16x8 v0 = *(const bf16x8*)&h2[((size_t)(2 * t)     * B_ + b) * H2_ + o0];
    const bf16x8 v1 = *(const bf16x8*)&h2[((size_t)(2 * t + 1) * B_ + b) * H2_ + o0];
    const bf16x8 v2 = *(const bf16x8*)&h2[((size_t)4           * B_ + b) * H2_ + o0];
    const bf16x8 v3 = *(const bf16x8*)&h2[((size_t)5           * B_ + b) * H2_ + o0];
    float r[8];
#pragma unroll
    for (int i = 0; i < 8; ++i)
        r[i] = g0 * (float)v0[i] + g1 * (float)v1[i]
             + g2 * (float)v2[i] + g3 * (float)v3[i];
    float4* op = (float4*)&out[(size_t)wid * H2_ + o0];
    op[0] = make_float4(r[0], r[1], r[2], r[3]);
    op[1] = make_float4(r[4], r[5], r[6], r[7]);
}

// ---------------------------------------------------------------------------
extern "C" void kernel_launch(void* const* d_in, const int* in_sizes, int n_in,
                              void* d_out, int out_size, void* d_ws, size_t ws_size,
                              hipStream_t stream)
{
    const float* x   = (const float*)d_in[0];
    const float* We1 = (const float*)d_in[1];
    const float* be1 = (const float*)d_in[2];
    const float* We2 = (const float*)d_in[3];
    const float* be2 = (const float*)d_in[4];
    const float* Wg1 = (const float*)d_in[5];
    const float* bg1 = (const float*)d_in[6];
    const float* Wgs = (const float*)d_in[7];
    float* out = (float*)d_out;

    char* ws = (char*)d_ws;
    bf16_t* x_bf = (bf16_t*)ws;  ws += (size_t)B_ * D_ * 2;              //  33.6 MB
    bf16_t* w1t  = (bf16_t*)ws;  ws += (size_t)7 * H1_ * D_ * 2;         //  29.4 MB (6 experts + gate)
    bf16_t* w2t  = (bf16_t*)ws;  ws += (size_t)E_ * H2_ * H1_ * 2;       //   6.3 MB
    bf16_t* h1   = (bf16_t*)ws;  ws += (size_t)7 * B_ * H1_ * 2;         // 117.4 MB (slice 6 = gate g)
    bf16_t* h2   = (bf16_t*)ws;  ws += (size_t)E_ * B_ * H2_ * 2;        //  50.3 MB

    bf16_t* wgt = w1t + (size_t)6 * H1_ * D_;   // gate weights = expert slice 6

    // 1) unified prep: transposes + x cast in one launch
    prep_kernel<<<dim3(32, 64, 18), dim3(32, 8), 0, stream>>>(
        x, We1, We2, Wg1, x_bf, w1t, w2t, wgt);

    // 2) GEMM1 + gate folded (z = 0..5 experts, z = 6 gate), 4p BK32 2/CU
    gemm256_4p32<<<dim3(H1_ / 256, B_ / 256, 7), 512, 0, stream>>>(
        x_bf, w1t, be1, bg1, h1, B_, H1_, D_, 0LL);

    // 3) GEMM2 over experts 0..5 (r4-proven kernel, writes h2)
    gemm_bn256_bias_relu<<<dim3(H2_ / 256, B_ / 128, E_), 512, 0, stream>>>(
        h1, w2t, be2, h2, B_, H2_, H1_, (long long)B_ * H1_);

    // 4) fused gate softmax + combine
    gate_combine_kernel<<<(T_ * B_) / 4, 256, 0, stream>>>(h1, h2, Wgs, out);
}

// Round 13
// 339.263 us; speedup vs baseline: 7.7994x; 7.7994x over previous
//
#include <hip/hip_runtime.h>
#include <hip/hip_bf16.h>
#include <cstdint>
#include <cstddef>

#define B_   8192
#define D_   2048
#define H1_  1024
#define H2_  512
#define G_   512
#define T_   2
#define E_   6
#define EC_  4

typedef __bf16 bf16_t;
typedef __attribute__((ext_vector_type(8))) __bf16 bf16x8;
typedef __attribute__((ext_vector_type(4))) float f32x4;

// ---------------------------------------------------------------------------
// async global->LDS, 16B per lane. LDS dest is wave-uniform base + lane*16.
// ---------------------------------------------------------------------------
__device__ __forceinline__ void gload_lds16(const bf16_t* g, bf16_t* l) {
    __builtin_amdgcn_global_load_lds(
        (const __attribute__((address_space(1))) bf16_t*)g,
        (__attribute__((address_space(3))) bf16_t*)l,
        16, 0, 0);
}

// ---------------------------------------------------------------------------
// unified prep: z 0..5 transpose We1 slices, 6..11 We2, 12..13 Wg1,
// 14..17 cast x -> bf16. Guards are block-uniform. grid (32,64,18), blk (32,8).
// ---------------------------------------------------------------------------
__global__ __launch_bounds__(256) void prep_kernel(
    const float* __restrict__ x,   const float* __restrict__ We1,
    const float* __restrict__ We2, const float* __restrict__ Wg1,
    bf16_t* __restrict__ x_bf, bf16_t* __restrict__ w1t,
    bf16_t* __restrict__ w2t,  bf16_t* __restrict__ wgt)
{
    __shared__ float tile[32][33];
    const int z  = blockIdx.z;
    const int bx = blockIdx.x, by = blockIdx.y;
    const int tx = threadIdx.x, ty = threadIdx.y;

    const float* src; bf16_t* dst; int R, C;
    if (z < 6) {
        src = We1 + (size_t)z * D_ * H1_;  dst = w1t + (size_t)z * H1_ * D_;
        R = D_;  C = H1_;
    } else if (z < 12) {
        if (bx >= 16 || by >= 32) return;
        src = We2 + (size_t)(z - 6) * H1_ * H2_;
        dst = w2t + (size_t)(z - 6) * H2_ * H1_;
        R = H1_; C = H2_;
    } else if (z < 14) {
        if (bx >= 16) return;
        src = Wg1 + (size_t)(z - 12) * D_ * G_;
        dst = wgt + (size_t)(z - 12) * G_ * D_;
        R = D_;  C = G_;
    } else {
        int i = ((z - 14) * 2048 + by * 32 + bx) * 256 + ty * 32 + tx;
        const float4* s = (const float4*)x + (size_t)i * 2;
        float4 a = s[0], b = s[1];
        bf16x8 o;
        o[0] = (bf16_t)a.x; o[1] = (bf16_t)a.y; o[2] = (bf16_t)a.z; o[3] = (bf16_t)a.w;
        o[4] = (bf16_t)b.x; o[5] = (bf16_t)b.y; o[6] = (bf16_t)b.z; o[7] = (bf16_t)b.w;
        *(bf16x8*)(x_bf + (size_t)i * 8) = o;
        return;
    }
    const int c0 = bx * 32, r0 = by * 32;
#pragma unroll
    for (int i = 0; i < 32; i += 8)
        tile[ty + i][tx] = src[(size_t)(r0 + ty + i) * C + (c0 + tx)];
    __syncthreads();
#pragma unroll
    for (int i = 0; i < 32; i += 8)
        dst[(size_t)(c0 + ty + i) * R + (r0 + tx)] = (bf16_t)tile[tx][ty + i];
}

// ---------------------------------------------------------------------------
// 256x256-tile, BK=64, 4-PHASE single-barrier GEMM (r11-proven, session best):
//   C = relu(A(M,K) * Bt(N,K)^T + bias), bf16 in/out, fp32 MFMA accumulate.
// 8 waves (2Mx4N), per-wave 128x64, acc = 128 AGPR -> REQUIRES
// __launch_bounds__(512, 2): 256-reg budget. (512,4) caps at 128 regs and
// spills the accumulator to scratch (r12: 12 GB scratch traffic, 10x slow).
// 4 phases/iter over 2 K-tiles; phase = {8 A-reads [+8 B-reads at qp==0] ||
// stages -> vmcnt(opt) -> barrier -> lgkm(0) -> 32 MFMA}.
// Wait ledger: end-P1 vmcnt(4) completes B(kt1),A(kt1) (needed P2), leaves
// B(kt0+2); end-P3 vmcnt(4) completes tile kt0+2 (needed next P0), leaves
// B(kt0+3); tail iter end-P1 vmcnt(0). Buffer overwrites keep the
// >=1-barrier margin validated r8-r11. Swizzle: chunk ^= row&7 (16B chunks)
// on BOTH stage-source and ds_read; measured conflict-free.
// bias: e<6 -> be1+e*H1, e==6 -> bg1.
// Requires: M%256==0, N%256==0, K%128==0, K/64>=4, gridX*gridY%8==0.
// ---------------------------------------------------------------------------
__global__ __launch_bounds__(512, 2) void gemm256_4p(
    const bf16_t* __restrict__ A, const bf16_t* __restrict__ Bt,
    const float* __restrict__ be1, const float* __restrict__ bg1,
    bf16_t* __restrict__ C, int M, int N, int K, long long strideA)
{
    const int e = blockIdx.z;
    A  += (size_t)e * (size_t)strideA;
    Bt += (size_t)e * (size_t)N * (size_t)K;
    C  += (size_t)e * (size_t)M * (size_t)N;
    const float* bias = (e < 6) ? (be1 + (size_t)e * H1_) : bg1;

    // T1: XCD swizzle within this z-slice (nwg % 8 == 0 by launch contract)
    const int gx  = gridDim.x;
    const int nwg = gx * gridDim.y;
    const int lin = blockIdx.y * gx + blockIdx.x;
    const int swz = (lin & 7) * (nwg >> 3) + (lin >> 3);
    const int row0 = (swz / gx) * 256;
    const int col0 = (swz % gx) * 256;

    __shared__ bf16_t lsA[2][16384];   // [dbuf][256 rows x 64], 64 KB
    __shared__ bf16_t lsB[2][16384];   // 64 KB

    const int tid  = threadIdx.x;
    const int lane = tid & 63;
    const int wave = tid >> 6;        // 0..7
    const int wr   = wave >> 2;       // 0..1 : M-half (128 rows)
    const int wc   = wave & 3;        // 0..3 : N-quarter (64 cols)

    // ---- staging: half-tile = 128 rows x 8 chunks(16B), chunk-XOR swizzle --
    size_t offG[2];
    int    ldsOff[2];
#pragma unroll
    for (int l = 0; l < 2; ++l) {
        int idx = l * 512 + tid;
        int r   = idx >> 3;                       // row within half, 0..127
        int c   = (idx & 7) ^ (r & 7);            // logical chunk
        offG[l]   = (size_t)r * (size_t)K + (size_t)(c * 8);
        ldsOff[l] = l * 4096 + wave * 512;        // elements, wave-uniform
    }
    const bf16_t* gA = A  + (size_t)row0 * (size_t)K;
    const bf16_t* gB = Bt + (size_t)col0 * (size_t)K;
    const size_t halfStride = (size_t)128 * (size_t)K;

    // ---- fragment read addressing (elements), same XOR involution ----------
    const int rbA = (wr * 128 + (lane & 15)) * 64;
    const int rbB = (wc * 64  + (lane & 15)) * 64;
    int xc[2];
#pragma unroll
    for (int ks = 0; ks < 2; ++ks)
        xc[ks] = (ks * 32 + ((lane >> 4) * 8)) ^ ((lane & 7) << 3);

    f32x4 acc[8][4];
#pragma unroll
    for (int m = 0; m < 8; ++m)
#pragma unroll
        for (int n = 0; n < 4; ++n)
            acc[m][n] = (f32x4){0.f, 0.f, 0.f, 0.f};

    const int nt    = K >> 6;         // K-tiles of 64
    const int niter = nt >> 1;        // 2 K-tiles per iteration

#define STAGE_A(dst, kt, h) do {                                              \
    _Pragma("unroll")                                                         \
    for (int l_ = 0; l_ < 2; ++l_)                                            \
        gload_lds16(gA + (size_t)((kt) * 64) + (size_t)(h) * halfStride       \
                       + offG[l_],                                            \
                    &lsA[dst][(h) * 8192 + ldsOff[l_]]);                      \
} while (0)

#define STAGE_B(dst, kt, h) do {                                              \
    _Pragma("unroll")                                                         \
    for (int l_ = 0; l_ < 2; ++l_)                                            \
        gload_lds16(gB + (size_t)((kt) * 64) + (size_t)(h) * halfStride       \
                       + offG[l_],                                            \
                    &lsB[dst][(h) * 8192 + ldsOff[l_]]);                      \
} while (0)

// merged phase qp (2 quadrants) of dbuf d: {8 A-reads [+8 B-reads if qp==0];
// stages; optional vmcnt; barrier; lgkm(0); 32 MFMA}. WAITV precedes barrier.
#define PHASE2(d, qp, STMT, WAITV) do {                                       \
    bf16x8 af[4][2];                                                          \
    _Pragma("unroll")                                                         \
    for (int q_ = 0; q_ < 4; ++q_) {                                          \
        af[q_][0] = *(const bf16x8*)&lsA[d][rbA + ((qp)*4+q_) * 1024 + xc[0]];\
        af[q_][1] = *(const bf16x8*)&lsA[d][rbA + ((qp)*4+q_) * 1024 + xc[1]];\
    }                                                                         \
    if ((qp) == 0) {                                                          \
        _Pragma("unroll")                                                     \
        for (int n_ = 0; n_ < 4; ++n_) {                                      \
            bfr[n_][0] = *(const bf16x8*)&lsB[d][rbB + n_ * 1024 + xc[0]];    \
            bfr[n_][1] = *(const bf16x8*)&lsB[d][rbB + n_ * 1024 + xc[1]];    \
        }                                                                     \
    }                                                                         \
    STMT;                                                                     \
    WAITV;                                                                    \
    __builtin_amdgcn_sched_barrier(0);                                        \
    __builtin_amdgcn_s_barrier();                                             \
    asm volatile("s_waitcnt lgkmcnt(0)" ::: "memory");                        \
    __builtin_amdgcn_sched_barrier(0);                                        \
    __builtin_amdgcn_s_setprio(1);                                            \
    _Pragma("unroll")                                                         \
    for (int q_ = 0; q_ < 4; ++q_) {                                          \
        _Pragma("unroll")                                                     \
        for (int n_ = 0; n_ < 4; ++n_) {                                      \
            acc[(qp)*4+q_][n_] = __builtin_amdgcn_mfma_f32_16x16x32_bf16(     \
                     af[q_][0], bfr[n_][0], acc[(qp)*4+q_][n_], 0, 0, 0);     \
            acc[(qp)*4+q_][n_] = __builtin_amdgcn_mfma_f32_16x16x32_bf16(     \
                     af[q_][1], bfr[n_][1], acc[(qp)*4+q_][n_], 0, 0, 0);     \
        }                                                                     \
    }                                                                         \
    __builtin_amdgcn_s_setprio(0);                                            \
    __builtin_amdgcn_sched_barrier(0);                                        \
} while (0)

    // ---- prologue: A(0),B(0) -> buf0; B(1) -> buf1; drain to 4 -------------
    STAGE_A(0, 0, 0); STAGE_A(0, 0, 1);
    STAGE_B(0, 0, 0); STAGE_B(0, 0, 1);
    STAGE_B(1, 1, 0); STAGE_B(1, 1, 1);
    asm volatile("s_waitcnt vmcnt(4)" ::: "memory");   // A(0),B(0) complete
    __builtin_amdgcn_sched_barrier(0);
    __builtin_amdgcn_s_barrier();
    __builtin_amdgcn_sched_barrier(0);

    // ---- main loop: iter i computes kt0=2i (buf0, P0-P1), kt1=2i+1 (buf1) --
    for (int i = 0; i < niter; ++i) {
        const int kt0 = 2 * i, kt1 = 2 * i + 1;
        const bool stg = (i + 1 < niter);
        bf16x8 bfr[4][2];

        PHASE2(0, 0, { STAGE_A(1, kt1, 0); STAGE_A(1, kt1, 1); }, {});
        PHASE2(0, 1, { if (stg) { STAGE_B(0, kt0 + 2, 0); STAGE_B(0, kt0 + 2, 1); } },
               { if (stg) { asm volatile("s_waitcnt vmcnt(4)" ::: "memory"); }
                 else     { asm volatile("s_waitcnt vmcnt(0)" ::: "memory"); } });
        PHASE2(1, 0, { if (stg) { STAGE_A(0, kt0 + 2, 0); STAGE_A(0, kt0 + 2, 1); } }, {});
        PHASE2(1, 1, { if (stg) { STAGE_B(1, kt0 + 3, 0); STAGE_B(1, kt0 + 3, 1); } },
               { if (stg) { asm volatile("s_waitcnt vmcnt(4)" ::: "memory"); } });
    }
#undef PHASE2
#undef STAGE_A
#undef STAGE_B

    // ---- epilogue: C/D layout col = lane&15, row = (lane>>4)*4 + j ----------
    const int crb = row0 + wr * 128 + ((lane >> 4) << 2);
    const int ccb = col0 + wc * 64  + (lane & 15);
#pragma unroll
    for (int n = 0; n < 4; ++n) {
        const int cc = ccb + n * 16;
        const float bv = bias[cc];
#pragma unroll
        for (int m = 0; m < 8; ++m) {
            const int rb = crb + m * 16;
#pragma unroll
            for (int j = 0; j < 4; ++j) {
                float v = acc[m][n][j] + bv;
                v = v > 0.f ? v : 0.f;
                C[(size_t)(rb + j) * N + cc] = (bf16_t)v;
            }
        }
    }
}

// ---------------------------------------------------------------------------
// r4-proven 128x256 GEMM, 2 blocks/CU — GEMM2 (writes h2 bf16).
// ---------------------------------------------------------------------------
__global__ __launch_bounds__(512, 4) void gemm_bn256_bias_relu(
    const bf16_t* __restrict__ A, const bf16_t* __restrict__ Bt,
    const float* __restrict__ bias, bf16_t* __restrict__ C,
    int M, int N, int K, long long strideA)
{
    const int e = blockIdx.z;
    A    += (size_t)e * (size_t)strideA;
    Bt   += (size_t)e * (size_t)N * (size_t)K;
    bias += (size_t)e * (size_t)N;
    C    += (size_t)e * (size_t)M * (size_t)N;

    const int gx  = gridDim.x;
    const int nwg = gx * gridDim.y;
    const int lin = blockIdx.y * gx + blockIdx.x;
    const int swz = (lin & 7) * (nwg >> 3) + (lin >> 3);
    const int row0 = (swz / gx) * 128;
    const int col0 = (swz % gx) * 256;

    __shared__ bf16_t lsA[3][128 * 32];   // 3 x 8 KB
    __shared__ bf16_t lsB[3][256 * 32];   // 3 x 16 KB   -> 72 KB total

    const int tid  = threadIdx.x;
    const int lane = tid & 63;
    const int wave = tid >> 6;        // 0..7
    const int wr   = wave >> 2;       // 0..1 : 64-row half
    const int wc   = wave & 3;        // 0..3 : 64-col quarter

    size_t offA, offB0, offB1;
    {
        int rA = tid >> 2, pA = tid & 3;
        offA = (size_t)rA * (size_t)K + (size_t)(((pA ^ (rA >> 1)) & 3) * 8);
        int r0_ = tid >> 2, p0_ = tid & 3;
        offB0 = (size_t)r0_ * (size_t)K + (size_t)(((p0_ ^ (r0_ >> 1)) & 3) * 8);
        int r1_ = (512 + tid) >> 2, p1_ = tid & 3;
        offB1 = (size_t)r1_ * (size_t)K + (size_t)(((p1_ ^ (r1_ >> 1)) & 3) * 8);
    }
    const int ldsA_off = wave * 512;
    const int ldsB0off = wave * 512;
    const int ldsB1off = 4096 + wave * 512;

    const bf16_t* gA = A  + (size_t)row0 * (size_t)K;
    const bf16_t* gB = Bt + (size_t)col0 * (size_t)K;

    const int xch  = ((lane >> 4) ^ ((lane >> 1) & 3)) << 3;
    const int aoff = (wr * 64 + (lane & 15)) * 32 + xch;
    const int boff = (wc * 64 + (lane & 15)) * 32 + xch;

    f32x4 acc[4][4];
#pragma unroll
    for (int m = 0; m < 4; ++m)
#pragma unroll
        for (int n = 0; n < 4; ++n)
            acc[m][n] = (f32x4){0.f, 0.f, 0.f, 0.f};

    const int nt = K >> 5;

#define STAGE(t_, c_) do {                                                    \
    const size_t kk_ = (size_t)(t_) * 32;                                     \
    gload_lds16(gA + kk_ + offA,  &lsA[c_][ldsA_off]);                        \
    gload_lds16(gB + kk_ + offB0, &lsB[c_][ldsB0off]);                        \
    gload_lds16(gB + kk_ + offB1, &lsB[c_][ldsB1off]);                        \
} while (0)

    STAGE(0, 0); STAGE(1, 1); STAGE(2, 2);
    asm volatile("s_waitcnt vmcnt(6)" ::: "memory");
    __builtin_amdgcn_s_barrier();
    __builtin_amdgcn_sched_barrier(0);

    int c = 0;
    for (int t = 0; t < nt; ++t) {
        bf16x8 a[4], b[4];
#pragma unroll
        for (int m = 0; m < 4; ++m)
            a[m] = *(const bf16x8*)&lsA[c][aoff + m * 512];
#pragma unroll
        for (int n = 0; n < 4; ++n)
            b[n] = *(const bf16x8*)&lsB[c][boff + n * 512];
        asm volatile("s_waitcnt lgkmcnt(0)" ::: "memory");
        __builtin_amdgcn_sched_barrier(0);
        __builtin_amdgcn_s_barrier();
        __builtin_amdgcn_sched_barrier(0);
        if (t + 3 < nt) STAGE(t + 3, c);
        __builtin_amdgcn_sched_barrier(0);
        __builtin_amdgcn_s_setprio(1);
#pragma unroll
        for (int m = 0; m < 4; ++m)
#pragma unroll
            for (int n = 0; n < 4; ++n)
                acc[m][n] = __builtin_amdgcn_mfma_f32_16x16x32_bf16(
                                a[m], b[n], acc[m][n], 0, 0, 0);
        __builtin_amdgcn_s_setprio(0);
        __builtin_amdgcn_sched_barrier(0);
        if (t + 3 < nt) { asm volatile("s_waitcnt vmcnt(6)" ::: "memory"); }
        else            { asm volatile("s_waitcnt vmcnt(0)" ::: "memory"); }
        __builtin_amdgcn_sched_barrier(0);
        __builtin_amdgcn_s_barrier();
        __builtin_amdgcn_sched_barrier(0);
        c = (c == 2) ? 0 : c + 1;
    }
#undef STAGE

    const int crb = row0 + wr * 64 + ((lane >> 4) << 2);
    const int ccb = col0 + wc * 64 + (lane & 15);
#pragma unroll
    for (int n = 0; n < 4; ++n) {
        const int cc = ccb + n * 16;
        const float bv = bias[cc];
#pragma unroll
        for (int m = 0; m < 4; ++m) {
            const int rb = crb + m * 16;
#pragma unroll
            for (int j = 0; j < 4; ++j) {
                float v = acc[m][n][j] + bv;
                v = v > 0.f ? v : 0.f;
                C[(size_t)(rb + j) * N + cc] = (bf16_t)v;
            }
        }
    }
}

// ---------------------------------------------------------------------------
// fused gate + combine (r9-proven): per wave, one (t,b) row.
// ---------------------------------------------------------------------------
__global__ __launch_bounds__(256) void gate_combine_kernel(
    const bf16_t* __restrict__ h1, const bf16_t* __restrict__ h2,
    const float* __restrict__ Wgs, float* __restrict__ out)
{
    int wid  = blockIdx.x * 4 + (threadIdx.x >> 6);   // t*B + b
    int lane = threadIdx.x & 63;
    int t = wid >> 13;                                // B_ = 8192
    int b = wid & (B_ - 1);

    const bf16_t* grow = h1 + ((size_t)(6 * B_) + b) * 1024 + t * G_;
    bf16x8 gv = *(const bf16x8*)&grow[lane * 8];
    const float* W = Wgs + (size_t)t * G_ * EC_;
    float a0 = 0.f, a1 = 0.f, a2 = 0.f, a3 = 0.f;
#pragma unroll
    for (int i = 0; i < 8; ++i) {
        float gvf = (float)gv[i];
        const float4 w = *(const float4*)&W[(size_t)(lane * 8 + i) * 4];
        a0 += gvf * w.x; a1 += gvf * w.y; a2 += gvf * w.z; a3 += gvf * w.w;
    }
#pragma unroll
    for (int off = 32; off; off >>= 1) {
        a0 += __shfl_xor(a0, off);
        a1 += __shfl_xor(a1, off);
        a2 += __shfl_xor(a2, off);
        a3 += __shfl_xor(a3, off);
    }
    float m  = fmaxf(fmaxf(a0, a1), fmaxf(a2, a3));
    float e0 = expf(a0 - m), e1 = expf(a1 - m), e2 = expf(a2 - m), e3 = expf(a3 - m);
    float inv = 1.f / (e0 + e1 + e2 + e3);
    float g0 = e0 * inv, g1 = e1 * inv, g2 = e2 * inv, g3 = e3 * inv;

    int o0 = lane * 8;                                // H2 = 512 = 64*8
    const bf16x8 v0 = *(const bf16x8*)&h2[((size_t)(2 * t)     * B_ + b) * H2_ + o0];
    const bf16x8 v1 = *(const bf16x8*)&h2[((size_t)(2 * t + 1) * B_ + b) * H2_ + o0];
    const bf16x8 v2 = *(const bf16x8*)&h2[((size_t)4           * B_ + b) * H2_ + o0];
    const bf16x8 v3 = *(const bf16x8*)&h2[((size_t)5           * B_ + b) * H2_ + o0];
    float r[8];
#pragma unroll
    for (int i = 0; i < 8; ++i)
        r[i] = g0 * (float)v0[i] + g1 * (float)v1[i]
             + g2 * (float)v2[i] + g3 * (float)v3[i];
    float4* op = (float4*)&out[(size_t)wid * H2_ + o0];
    op[0] = make_float4(r[0], r[1], r[2], r[3]);
    op[1] = make_float4(r[4], r[5], r[6], r[7]);
}

// ---------------------------------------------------------------------------
extern "C" void kernel_launch(void* const* d_in, const int* in_sizes, int n_in,
                              void* d_out, int out_size, void* d_ws, size_t ws_size,
                              hipStream_t stream)
{
    const float* x   = (const float*)d_in[0];
    const float* We1 = (const float*)d_in[1];
    const float* be1 = (const float*)d_in[2];
    const float* We2 = (const float*)d_in[3];
    const float* be2 = (const float*)d_in[4];
    const float* Wg1 = (const float*)d_in[5];
    const float* bg1 = (const float*)d_in[6];
    const float* Wgs = (const float*)d_in[7];
    float* out = (float*)d_out;

    char* ws = (char*)d_ws;
    bf16_t* x_bf = (bf16_t*)ws;  ws += (size_t)B_ * D_ * 2;              //  33.6 MB
    bf16_t* w1t  = (bf16_t*)ws;  ws += (size_t)7 * H1_ * D_ * 2;         //  29.4 MB (6 experts + gate)
    bf16_t* w2t  = (bf16_t*)ws;  ws += (size_t)E_ * H2_ * H1_ * 2;       //   6.3 MB
    bf16_t* h1   = (bf16_t*)ws;  ws += (size_t)7 * B_ * H1_ * 2;         // 117.4 MB (slice 6 = gate g)
    bf16_t* h2   = (bf16_t*)ws;  ws += (size_t)E_ * B_ * H2_ * 2;        //  50.3 MB

    bf16_t* wgt = w1t + (size_t)6 * H1_ * D_;   // gate weights = expert slice 6

    // 1) unified prep: transposes + x cast in one launch
    prep_kernel<<<dim3(32, 64, 18), dim3(32, 8), 0, stream>>>(
        x, We1, We2, Wg1, x_bf, w1t, w2t, wgt);

    // 2) GEMM1 + gate folded (z = 0..5 experts, z = 6 gate), 4-phase 256^2
    gemm256_4p<<<dim3(H1_ / 256, B_ / 256, 7), 512, 0, stream>>>(
        x_bf, w1t, be1, bg1, h1, B_, H1_, D_, 0LL);

    // 3) GEMM2 over experts 0..5 (r4-proven kernel, writes h2)
    gemm_bn256_bias_relu<<<dim3(H2_ / 256, B_ / 128, E_), 512, 0, stream>>>(
        h1, w2t, be2, h2, B_, H2_, H1_, (long long)B_ * H1_);

    // 4) fused gate softmax + combine
    gate_combine_kernel<<<(T_ * B_) / 4, 256, 0, stream>>>(h1, h2, Wgs, out);
}